// Round 1
// baseline (56.451 us; speedup 1.0000x reference)
//
#include <hip/hip_runtime.h>
#include <hip/hip_bf16.h>

// GaussianKernel: S[i][j] = exp(-||H1_i - H2_j||^2), N1=N2=8192, K=64, fp32.
// Strategy: split-bf16 MFMA (hi/lo planes, 3 mfma passes) -> store-bound.

typedef float  f32x4   __attribute__((ext_vector_type(4)));
typedef float  float4v __attribute__((ext_vector_type(4)));
typedef short  short8  __attribute__((ext_vector_type(8)));
typedef unsigned short ushort8 __attribute__((ext_vector_type(8)));

#define TM 128
#define TN 128
#define KD 64

__device__ __forceinline__ unsigned short f2bf(float x) {
    __hip_bfloat16 h = __float2bfloat16(x);   // RNE
    unsigned short u;
    __builtin_memcpy(&u, &h, 2);
    return u;
}
__device__ __forceinline__ float bf2f(unsigned short u) {
    unsigned int v = ((unsigned int)u) << 16;
    float f;
    __builtin_memcpy(&f, &v, 4);
    return f;
}

__global__ __launch_bounds__(256, 2) void gauss_mfma(
    const float* __restrict__ H1, const float* __restrict__ H2,
    float* __restrict__ out, int N1, int N2)
{
    // hi/lo bf16 planes for A (rows of H1) and B (rows of H2), XOR-swizzled.
    __shared__ __align__(16) unsigned short sAhi[TM * KD];
    __shared__ __align__(16) unsigned short sAlo[TM * KD];
    __shared__ __align__(16) unsigned short sBhi[TN * KD];
    __shared__ __align__(16) unsigned short sBlo[TN * KD];
    __shared__ float snrm[TM + TN];

    const int t = threadIdx.x;          // 0..255
    const int row0 = blockIdx.y * TM;
    const int col0 = blockIdx.x * TN;

    // ---- stage: coalesced float8 chunks, convert fp32 -> bf16 hi/lo ----
    // Each side panel = 128 rows * 64 floats = 1024 float8 chunks.
    #pragma unroll
    for (int side = 0; side < 2; ++side) {
        const float* src = side ? (H2 + (size_t)col0 * KD)
                                : (H1 + (size_t)row0 * KD);
        unsigned short* hi = side ? sBhi : sAhi;
        unsigned short* lo = side ? sBlo : sAlo;
        #pragma unroll
        for (int i = 0; i < 4; ++i) {
            int g   = i * 256 + t;       // float8 chunk id, 0..1023
            int row = g >> 3;            // 0..127
            int kc  = g & 7;             // which 8-float chunk in the row
            const float4v* p = (const float4v*)(src + (size_t)g * 8);
            float4v v0 = p[0], v1 = p[1];
            ushort8 h, l;
            #pragma unroll
            for (int e = 0; e < 8; ++e) {
                float a = (e < 4) ? v0[e] : v1[e - 4];
                unsigned short hb = f2bf(a);
                float r = a - bf2f(hb);
                h[e] = hb;
                l[e] = f2bf(r);
            }
            unsigned int off = (unsigned)(row * (KD * 2) + kc * 16);
            off ^= (unsigned)((row & 7) << 4);           // bank swizzle
            *(ushort8*)((char*)hi + off) = h;
            *(ushort8*)((char*)lo + off) = l;
        }
    }
    __syncthreads();

    // ---- per-row squared norms from the staged hi+lo planes ----
    {
        const unsigned short* hi = (t < TM) ? sAhi : sBhi;
        const unsigned short* lo = (t < TM) ? sAlo : sBlo;
        int row = (t < TM) ? t : (t - TM);
        float s = 0.f;
        #pragma unroll
        for (int kc = 0; kc < 8; ++kc) {
            unsigned int off = (unsigned)(row * (KD * 2) + kc * 16)
                             ^ (unsigned)((row & 7) << 4);
            ushort8 h = *(const ushort8*)((const char*)hi + off);
            ushort8 l = *(const ushort8*)((const char*)lo + off);
            #pragma unroll
            for (int e = 0; e < 8; ++e) {
                float a = bf2f(h[e]) + bf2f(l[e]);
                s = fmaf(a, a, s);
            }
        }
        snrm[t] = s;
    }
    __syncthreads();

    // ---- MFMA: 4 waves, each a 64x64 sub-tile = 4x4 fragments 16x16 ----
    const int lane = t & 63;
    const int w    = t >> 6;
    const int wr   = w >> 1, wc = w & 1;
    const int lr   = lane & 15;          // A-row / B-col within fragment
    const int kb   = lane >> 4;          // k-block 0..3 (8 elems each)

    f32x4 acc[4][4];
    #pragma unroll
    for (int a = 0; a < 4; ++a)
        #pragma unroll
        for (int b = 0; b < 4; ++b)
            acc[a][b] = (f32x4){0.f, 0.f, 0.f, 0.f};

    #pragma unroll
    for (int ks = 0; ks < 2; ++ks) {
        short8 bh[4], bl[4];
        #pragma unroll
        for (int fc = 0; fc < 4; ++fc) {
            int rowb = wc * 64 + fc * 16 + lr;
            unsigned int off = (unsigned)(rowb * (KD * 2) + ks * 64 + kb * 16)
                             ^ (unsigned)((rowb & 7) << 4);
            bh[fc] = *(const short8*)((const char*)sBhi + off);
            bl[fc] = *(const short8*)((const char*)sBlo + off);
        }
        #pragma unroll
        for (int fr = 0; fr < 4; ++fr) {
            int rowa = wr * 64 + fr * 16 + lr;
            unsigned int off = (unsigned)(rowa * (KD * 2) + ks * 64 + kb * 16)
                             ^ (unsigned)((rowa & 7) << 4);
            short8 ah = *(const short8*)((const char*)sAhi + off);
            short8 al = *(const short8*)((const char*)sAlo + off);
            #pragma unroll
            for (int fc = 0; fc < 4; ++fc) {
                acc[fr][fc] = __builtin_amdgcn_mfma_f32_16x16x32_bf16(
                                  ah, bh[fc], acc[fr][fc], 0, 0, 0);
                acc[fr][fc] = __builtin_amdgcn_mfma_f32_16x16x32_bf16(
                                  ah, bl[fc], acc[fr][fc], 0, 0, 0);
                acc[fr][fc] = __builtin_amdgcn_mfma_f32_16x16x32_bf16(
                                  al, bh[fc], acc[fr][fc], 0, 0, 0);
            }
        }
    }

    // ---- epilogue: D2 = n1 + n2 - 2*dot ; out = exp(-D2) ----
    // C/D layout (verified m89/m91): col = lane&15, row = (lane>>4)*4 + j
    const int r4 = (lane >> 4) * 4;
    #pragma unroll
    for (int fr = 0; fr < 4; ++fr) {
        int rloc = wr * 64 + fr * 16 + r4;
        #pragma unroll
        for (int fc = 0; fc < 4; ++fc) {
            int cloc = wc * 64 + fc * 16 + lr;
            float n2v = snrm[TM + cloc];
            size_t gc = (size_t)(col0 + cloc);
            #pragma unroll
            for (int j = 0; j < 4; ++j) {
                float n1v = snrm[rloc + j];
                float d2  = n1v + n2v - 2.0f * acc[fr][fc][j];
                out[(size_t)(row0 + rloc + j) * (size_t)N2 + gc] = __expf(-d2);
            }
        }
    }
}

extern "C" void kernel_launch(void* const* d_in, const int* in_sizes, int n_in,
                              void* d_out, int out_size, void* d_ws, size_t ws_size,
                              hipStream_t stream) {
    const float* H1 = (const float*)d_in[0];
    const float* H2 = (const float*)d_in[1];
    float* out = (float*)d_out;
    const int n1 = in_sizes[0] / KD;   // 8192
    const int n2 = in_sizes[1] / KD;   // 8192
    dim3 grid(n2 / TN, n1 / TM);
    gauss_mfma<<<grid, dim3(256), 0, stream>>>(H1, H2, out, n1, n2);
}